// Round 1
// baseline (538.110 us; speedup 1.0000x reference)
//
#include <hip/hip_runtime.h>

typedef __attribute__((ext_vector_type(8))) short s16x8;
typedef __attribute__((ext_vector_type(4))) float f32x4;

__device__ inline float bf2f(ushort u) {
    union { unsigned int i; float f; } v; v.i = ((unsigned)u) << 16; return v.f;
}
__device__ inline ushort f2bf(float f) {
    union { float f; unsigned int i; } v; v.f = f;
    unsigned r = v.i + 0x7FFFu + ((v.i >> 16) & 1u);
    return (ushort)(r >> 16);
}
__device__ inline float silu_f(float x) { return x / (1.f + __expf(-x)); }

// K1: x = node_features @ W_up, stored bf16. 4 nodes/block.
__global__ __launch_bounds__(256) void node_up_kernel(const float* __restrict__ nf,
                                                      const float* __restrict__ W_up,
                                                      ushort* __restrict__ x_ws) {
    __shared__ float sW[64 * 64];
    __shared__ float sNf[4][64];
    int tid = threadIdx.x;
    size_t n0 = (size_t)blockIdx.x * 4;
    for (int i = tid; i < 4096; i += 256) sW[i] = W_up[i];
    {
        int r = tid >> 6, c = tid & 63;
        sNf[r][c] = nf[(n0 + r) * 64 + c];
    }
    __syncthreads();
    int r = tid >> 6, k = tid & 63;
    float acc = 0.f;
    #pragma unroll 8
    for (int c = 0; c < 64; ++c) acc += sNf[r][c] * sW[c * 64 + k];
    x_ws[(n0 + r) * 64 + k] = f2bf(acc);
}

// K2: histogram of receivers
__global__ __launch_bounds__(256) void hist_kernel(const int* __restrict__ recv,
                                                   int* __restrict__ counts, int E) {
    int e = blockIdx.x * 256 + threadIdx.x;
    if (e < E) atomicAdd(&counts[recv[e]], 1);
}

// K3: single-block exclusive scan counts -> offsets (and cursor copy)
__global__ __launch_bounds__(1024) void scan_kernel(const int* __restrict__ counts,
                                                    int* __restrict__ offsets,
                                                    int* __restrict__ cursor, int n) {
    __shared__ int wsums[16];
    __shared__ int s_carry;
    int tid = threadIdx.x, lane = tid & 63, wid = tid >> 6;
    if (tid == 0) s_carry = 0;
    __syncthreads();
    for (int base = 0; base < n; base += 1024) {
        int i = base + tid;
        int orig = (i < n) ? counts[i] : 0;
        int v = orig;
        for (int off = 1; off < 64; off <<= 1) {
            int t = __shfl_up(v, off, 64);
            if (lane >= off) v += t;
        }
        if (lane == 63) wsums[wid] = v;
        __syncthreads();
        if (tid == 0) {
            int acc = 0;
            for (int w = 0; w < 16; ++w) { acc += wsums[w]; wsums[w] = acc; }
        }
        __syncthreads();
        int wprefix = (wid > 0) ? wsums[wid - 1] : 0;
        int excl = s_carry + wprefix + v - orig;
        if (i < n) { offsets[i] = excl; cursor[i] = excl; }
        __syncthreads();
        if (tid == 0) s_carry += wsums[15];
        __syncthreads();
    }
    if (tid == 0) offsets[n] = s_carry;
}

// K4: scatter edge ids into CSR order
__global__ __launch_bounds__(256) void scatter_kernel(const int* __restrict__ recv,
                                                      int* __restrict__ cursor,
                                                      int* __restrict__ edge_ids, int E) {
    int e = blockIdx.x * 256 + threadIdx.x;
    if (e < E) {
        int pos = atomicAdd(&cursor[recv[e]], 1);
        edge_ids[pos] = e;
    }
}

// K5: edge MLP: radial(E,8) -> silu MLP -> tp_w (E,256) bf16. 64 edges/block, MFMA 16x16x32.
__global__ __launch_bounds__(256) void edge_mlp_kernel(const float* __restrict__ radial,
                                                       const float* __restrict__ W1,
                                                       const float* __restrict__ W2,
                                                       const float* __restrict__ W3,
                                                       const float* __restrict__ W4,
                                                       ushort* __restrict__ tpw, int E) {
    __shared__ __align__(16) ushort sW2t[64 * 72];
    __shared__ __align__(16) ushort sW3t[64 * 72];
    __shared__ __align__(16) ushort sW4t[256 * 72];
    __shared__ __align__(16) ushort hA[64 * 72];
    __shared__ __align__(16) ushort hB[64 * 72];
    __shared__ float sW1[8 * 64];
    __shared__ float sRad[64 * 8];
    int tid = threadIdx.x;
    size_t e0 = (size_t)blockIdx.x * 64;

    for (int i = tid; i < 512; i += 256) sW1[i] = W1[i];
    for (int i = tid; i < 4096; i += 256) {
        int k = i >> 6, c = i & 63;
        sW2t[c * 72 + k] = f2bf(W2[i]);
        sW3t[c * 72 + k] = f2bf(W3[i]);
    }
    for (int i = tid; i < 16384; i += 256) {
        int k = i >> 8, c = i & 255;
        sW4t[c * 72 + k] = f2bf(W4[i]);
    }
    if (tid < 128) {
        int e = tid >> 1, half = tid & 1;
        if (e0 + e < (size_t)E)
            *(float4*)&sRad[e * 8 + half * 4] =
                *(const float4*)&radial[(e0 + e) * 8 + half * 4];
    }
    __syncthreads();

    // layer 1 (K=8, VALU)
    {
        int e = tid & 63, kg = tid >> 6;
        for (int k = kg * 16; k < kg * 16 + 16; ++k) {
            float acc = 0.f;
            #pragma unroll
            for (int d = 0; d < 8; ++d) acc += sRad[e * 8 + d] * sW1[d * 64 + k];
            hA[e * 72 + k] = f2bf(silu_f(acc));
        }
    }
    __syncthreads();

    int lane = tid & 63, wave = tid >> 6;
    int r0 = wave * 16;
    int arow = (r0 + (lane & 15)) * 72 + (lane >> 4) * 8;
    int brow = (lane & 15) * 72 + (lane >> 4) * 8;

    auto do_layer = [&](const ushort* hin, ushort* hout, const ushort* wt) {
        for (int nt = 0; nt < 4; ++nt) {
            f32x4 acc = {0.f, 0.f, 0.f, 0.f};
            #pragma unroll
            for (int ks = 0; ks < 2; ++ks) {
                s16x8 a = *(const s16x8*)(hin + arow + ks * 32);
                s16x8 b = *(const s16x8*)(wt + nt * 16 * 72 + brow + ks * 32);
                acc = __builtin_amdgcn_mfma_f32_16x16x32_bf16(a, b, acc, 0, 0, 0);
            }
            #pragma unroll
            for (int r = 0; r < 4; ++r) {
                int row = r0 + (lane >> 4) * 4 + r;
                int col = nt * 16 + (lane & 15);
                hout[row * 72 + col] = f2bf(silu_f(acc[r]));
            }
        }
    };
    do_layer(hA, hB, sW2t);
    do_layer(hB, hA, sW3t);

    // layer 4: hA(64x64) @ W4t -> tp_w global (no activation)
    for (int nt = 0; nt < 16; ++nt) {
        f32x4 acc = {0.f, 0.f, 0.f, 0.f};
        #pragma unroll
        for (int ks = 0; ks < 2; ++ks) {
            s16x8 a = *(const s16x8*)(hA + arow + ks * 32);
            s16x8 b = *(const s16x8*)(sW4t + nt * 16 * 72 + brow + ks * 32);
            acc = __builtin_amdgcn_mfma_f32_16x16x32_bf16(a, b, acc, 0, 0, 0);
        }
        #pragma unroll
        for (int r = 0; r < 4; ++r) {
            size_t row = e0 + r0 + (lane >> 4) * 4 + r;
            int col = nt * 16 + (lane & 15);
            if (row < (size_t)E) tpw[row * 256 + col] = f2bf(acc[r]);
        }
    }
}

// K6: per-node aggregation + linear mixes + output. One block (256 thr) per node.
__global__ __launch_bounds__(256) void node_out_kernel(
    const float* __restrict__ nf, const float* __restrict__ one_hot,
    const float* __restrict__ angular, const float* __restrict__ W_lin,
    const float* __restrict__ W_skip, const float* __restrict__ W_c0,
    const float* __restrict__ W_c1, const float* __restrict__ W_p0,
    const float* __restrict__ W_p1, const int* __restrict__ sender,
    const int* __restrict__ offsets, const int* __restrict__ edge_ids,
    const ushort* __restrict__ x_ws, const ushort* __restrict__ tpw,
    float* __restrict__ out) {
    __shared__ float sAgg[16][68];
    __shared__ float sFeats[16][68];
    __shared__ __align__(16) ushort sWlin[4 * 64 * 64];
    __shared__ float snf[64], swn0[64], swn1[64];
    __shared__ int sElem;
    int n = blockIdx.x, tid = threadIdx.x;

    if (tid == 0) {
        int e = 0;
        for (int a = 0; a < 10; ++a)
            if (one_hot[n * 10 + a] > 0.5f) { e = a; break; }
        sElem = e;
    }
    for (int i = tid; i < 16384; i += 256) sWlin[i] = f2bf(W_lin[i]);
    if (tid < 64) snf[tid] = nf[(size_t)n * 64 + tid];
    __syncthreads();
    int elem = sElem;
    if (tid < 64) {
        swn0[tid] = W_c0[elem * 64 + tid];
        swn1[tid] = W_c1[elem * 64 + tid];
    }

    int m = tid >> 4, c0 = (tid & 15) * 4;
    int l = (m == 0) ? 0 : ((m < 4) ? 1 : ((m < 9) ? 2 : 3));
    float a0 = 0, a1 = 0, a2 = 0, a3 = 0;
    int beg = offsets[n], end = offsets[n + 1];
    for (int i = beg; i < end; ++i) {
        int eid = edge_ids[i];
        int s = sender[eid];
        float ang = angular[(size_t)eid * 16 + m];
        ushort4 xv = *(const ushort4*)(x_ws + (size_t)s * 64 + c0);
        ushort4 wv = *(const ushort4*)(tpw + (size_t)eid * 256 + l * 64 + c0);
        a0 += ang * bf2f(xv.x) * bf2f(wv.x);
        a1 += ang * bf2f(xv.y) * bf2f(wv.y);
        a2 += ang * bf2f(xv.z) * bf2f(wv.z);
        a3 += ang * bf2f(xv.w) * bf2f(wv.w);
    }
    sAgg[m][c0 + 0] = a0 * 0.1f;
    sAgg[m][c0 + 1] = a1 * 0.1f;
    sAgg[m][c0 + 2] = a2 * 0.1f;
    sAgg[m][c0 + 3] = a3 * 0.1f;
    __syncthreads();

    {   // feats[m] = agg[m] @ W_lin[l(m)]
        int k0 = c0;
        float f0 = 0, f1 = 0, f2 = 0, f3 = 0;
        const ushort* wl = sWlin + l * 4096 + k0;
        #pragma unroll 4
        for (int c = 0; c < 64; ++c) {
            float av = sAgg[m][c];
            ushort4 w = *(const ushort4*)(wl + c * 64);
            f0 += av * bf2f(w.x);
            f1 += av * bf2f(w.y);
            f2 += av * bf2f(w.z);
            f3 += av * bf2f(w.w);
        }
        sFeats[m][k0 + 0] = f0;
        sFeats[m][k0 + 1] = f1;
        sFeats[m][k0 + 2] = f2;
        sFeats[m][k0 + 3] = f3;
    }
    __syncthreads();

    if (tid < 64) {
        int k = tid;
        float acc = 0.f;
        #pragma unroll 4
        for (int c = 0; c < 64; ++c) {
            acc += sFeats[0][c] * swn0[c] * W_p0[c * 64 + k];
            acc += snf[c] * W_skip[(c * 10 + elem) * 64 + k];
        }
        out[(size_t)n * 256 + k] = acc;
    } else {
        int idx = tid - 64, mm = idx >> 6, k = idx & 63;
        float acc = 0.f;
        #pragma unroll 4
        for (int c = 0; c < 64; ++c)
            acc += sFeats[1 + mm][c] * swn1[c] * W_p1[c * 64 + k];
        out[(size_t)n * 256 + 64 + k * 3 + mm] = acc;
    }
}

extern "C" void kernel_launch(void* const* d_in, const int* in_sizes, int n_in,
                              void* d_out, int out_size, void* d_ws, size_t ws_size,
                              hipStream_t stream) {
    const float* node_features = (const float*)d_in[0];
    const float* one_hot = (const float*)d_in[1];
    const float* angular = (const float*)d_in[2];
    const float* radial = (const float*)d_in[3];
    const float* W_up = (const float*)d_in[4];
    const float* W_mlp1 = (const float*)d_in[5];
    const float* W_mlp2 = (const float*)d_in[6];
    const float* W_mlp3 = (const float*)d_in[7];
    const float* W_mlp4 = (const float*)d_in[8];
    const float* W_lin = (const float*)d_in[9];
    const float* W_skip = (const float*)d_in[10];
    const float* W_c0 = (const float*)d_in[11];
    const float* W_c1 = (const float*)d_in[12];
    const float* W_p0 = (const float*)d_in[13];
    const float* W_p1 = (const float*)d_in[14];
    const int* edge_index = (const int*)d_in[15];
    float* out = (float*)d_out;

    int N = in_sizes[0] / 64;
    int E = in_sizes[2] / 16;
    const int* sender = edge_index;
    const int* receiver = edge_index + E;

    char* p = (char*)d_ws;
    ushort* x_ws = (ushort*)p;  p += (size_t)N * 64 * 2;
    ushort* tpw = (ushort*)p;   p += (size_t)E * 256 * 2;
    int* counts = (int*)p;      p += (size_t)N * 4;
    int* offsets = (int*)p;     p += (size_t)(N + 1) * 4;
    int* cursor = (int*)p;      p += (size_t)N * 4;
    int* edge_ids = (int*)p;    p += (size_t)E * 4;

    hipMemsetAsync(counts, 0, (size_t)N * 4, stream);
    node_up_kernel<<<N / 4, 256, 0, stream>>>(node_features, W_up, x_ws);
    hist_kernel<<<(E + 255) / 256, 256, 0, stream>>>(receiver, counts, E);
    scan_kernel<<<1, 1024, 0, stream>>>(counts, offsets, cursor, N);
    scatter_kernel<<<(E + 255) / 256, 256, 0, stream>>>(receiver, cursor, edge_ids, E);
    edge_mlp_kernel<<<(E + 63) / 64, 256, 0, stream>>>(radial, W_mlp1, W_mlp2, W_mlp3,
                                                       W_mlp4, tpw, E);
    node_out_kernel<<<N, 256, 0, stream>>>(node_features, one_hot, angular, W_lin,
                                           W_skip, W_c0, W_c1, W_p0, W_p1, sender,
                                           offsets, edge_ids, x_ws, tpw, out);
}

// Round 2
// 207.854 us; speedup vs baseline: 2.5889x; 2.5889x over previous
//
#include <hip/hip_runtime.h>

typedef __attribute__((ext_vector_type(8))) short s16x8;
typedef __attribute__((ext_vector_type(4))) float f32x4;

__device__ inline float bf2f(ushort u) {
    union { unsigned int i; float f; } v; v.i = ((unsigned)u) << 16; return v.f;
}
__device__ inline ushort f2bf(float f) {
    union { float f; unsigned int i; } v; v.f = f;
    unsigned r = v.i + 0x7FFFu + ((v.i >> 16) & 1u);
    return (ushort)(r >> 16);
}
__device__ inline float silu_f(float x) { return x / (1.f + __expf(-x)); }

// K1: x = node_features @ W_up, stored bf16. 4 nodes/block.
__global__ __launch_bounds__(256) void node_up_kernel(const float* __restrict__ nf,
                                                      const float* __restrict__ W_up,
                                                      ushort* __restrict__ x_ws) {
    __shared__ float sW[64 * 64];
    __shared__ float sNf[4][64];
    int tid = threadIdx.x;
    size_t n0 = (size_t)blockIdx.x * 4;
    for (int i = tid; i < 4096; i += 256) sW[i] = W_up[i];
    {
        int r = tid >> 6, c = tid & 63;
        sNf[r][c] = nf[(n0 + r) * 64 + c];
    }
    __syncthreads();
    int r = tid >> 6, k = tid & 63;
    float acc = 0.f;
    #pragma unroll 8
    for (int c = 0; c < 64; ++c) acc += sNf[r][c] * sW[c * 64 + k];
    x_ws[(n0 + r) * 64 + k] = f2bf(acc);
}

// K2: histogram of receivers
__global__ __launch_bounds__(256) void hist_kernel(const int* __restrict__ recv,
                                                   int* __restrict__ counts, int E) {
    int e = blockIdx.x * 256 + threadIdx.x;
    if (e < E) atomicAdd(&counts[recv[e]], 1);
}

// K3: single-pass chunked exclusive scan counts -> offsets (and cursor copy)
__global__ __launch_bounds__(1024) void scan_kernel(const int* __restrict__ counts,
                                                    int* __restrict__ offsets,
                                                    int* __restrict__ cursor, int n) {
    __shared__ int wsums[16];
    int tid = threadIdx.x, lane = tid & 63, wid = tid >> 6;
    int CH = (n + 1023) >> 10;
    int base = tid * CH;
    int tot = 0;
    for (int j = 0; j < CH; ++j) {
        int i = base + j;
        if (i < n) tot += counts[i];
    }
    int v = tot;
    for (int off = 1; off < 64; off <<= 1) {
        int t = __shfl_up(v, off, 64);
        if (lane >= off) v += t;
    }
    if (lane == 63) wsums[wid] = v;
    __syncthreads();
    if (tid == 0) {
        int acc = 0;
        for (int w = 0; w < 16; ++w) { int t = wsums[w]; wsums[w] = acc; acc += t; }
    }
    __syncthreads();
    int excl = wsums[wid] + v - tot;
    for (int j = 0; j < CH; ++j) {
        int i = base + j;
        if (i < n) { offsets[i] = excl; cursor[i] = excl; excl += counts[i]; }
    }
    if (tid == 1023) offsets[n] = excl;
}

// K4: scatter edge ids into CSR order
__global__ __launch_bounds__(256) void scatter_kernel(const int* __restrict__ recv,
                                                      int* __restrict__ cursor,
                                                      int* __restrict__ edge_ids, int E) {
    int e = blockIdx.x * 256 + threadIdx.x;
    if (e < E) {
        int pos = atomicAdd(&cursor[recv[e]], 1);
        edge_ids[pos] = e;
    }
}

// K_prep: convert MLP weights to bf16 transposed (stride-72) images for direct LDS copy.
// layout in wp (ushorts): [0,4608) W2t, [4608,9216) W3t, [9216,18432) W4t (first 128 cols)
__global__ __launch_bounds__(256) void prep_kernel(const float* __restrict__ W2,
                                                   const float* __restrict__ W3,
                                                   const float* __restrict__ W4,
                                                   ushort* __restrict__ wp) {
    int e = blockIdx.x * 256 + threadIdx.x;
    if (e < 4608) {
        int c = e / 72, k = e % 72;
        wp[e] = (k < 64) ? f2bf(W2[k * 64 + c]) : (ushort)0;
    } else if (e < 9216) {
        int i = e - 4608, c = i / 72, k = i % 72;
        wp[e] = (k < 64) ? f2bf(W3[k * 64 + c]) : (ushort)0;
    } else if (e < 18432) {
        int i = e - 9216, c = i / 72, k = i % 72;
        wp[e] = (k < 64) ? f2bf(W4[k * 256 + c]) : (ushort)0;
    }
}

// K5: edge MLP: radial(E,8) -> silu MLP -> tp_w (E,128) bf16 (only l=0,1 needed).
__global__ __launch_bounds__(256) void edge_mlp_kernel(const float* __restrict__ radial,
                                                       const float* __restrict__ W1,
                                                       const ushort* __restrict__ wp,
                                                       ushort* __restrict__ tpw, int E) {
    __shared__ __align__(16) ushort sW[18432];  // W2t | W3t | W4t(128 cols)
    __shared__ __align__(16) ushort hA[64 * 72];
    __shared__ __align__(16) ushort hB[64 * 72];
    __shared__ float sW1[8 * 64];
    __shared__ float sRad[64 * 8];
    int tid = threadIdx.x;
    size_t e0 = (size_t)blockIdx.x * 64;

    for (int i = tid; i < 2304; i += 256)
        ((s16x8*)sW)[i] = ((const s16x8*)wp)[i];
    for (int i = tid; i < 512; i += 256) sW1[i] = W1[i];
    if (tid < 128) {
        int e = tid >> 1, half = tid & 1;
        *(float4*)&sRad[e * 8 + half * 4] =
            *(const float4*)&radial[(e0 + e) * 8 + half * 4];
    }
    __syncthreads();

    // layer 1 (K=8, VALU)
    {
        int e = tid & 63, kg = tid >> 6;
        for (int k = kg * 16; k < kg * 16 + 16; ++k) {
            float acc = 0.f;
            #pragma unroll
            for (int d = 0; d < 8; ++d) acc += sRad[e * 8 + d] * sW1[d * 64 + k];
            hA[e * 72 + k] = f2bf(silu_f(acc));
        }
    }
    __syncthreads();

    int lane = tid & 63, wave = tid >> 6;
    int r0 = wave * 16;
    int arow = (r0 + (lane & 15)) * 72 + (lane >> 4) * 8;
    int brow = (lane & 15) * 72 + (lane >> 4) * 8;

    auto do_layer = [&](const ushort* hin, ushort* hout, const ushort* wt) {
        for (int nt = 0; nt < 4; ++nt) {
            f32x4 acc = {0.f, 0.f, 0.f, 0.f};
            #pragma unroll
            for (int ks = 0; ks < 2; ++ks) {
                s16x8 a = *(const s16x8*)(hin + arow + ks * 32);
                s16x8 b = *(const s16x8*)(wt + nt * 16 * 72 + brow + ks * 32);
                acc = __builtin_amdgcn_mfma_f32_16x16x32_bf16(a, b, acc, 0, 0, 0);
            }
            #pragma unroll
            for (int r = 0; r < 4; ++r) {
                int row = r0 + (lane >> 4) * 4 + r;
                int col = nt * 16 + (lane & 15);
                hout[row * 72 + col] = f2bf(silu_f(acc[r]));
            }
        }
    };
    do_layer(hA, hB, sW);
    do_layer(hB, hA, sW + 4608);

    // layer 4: hA(64x64) @ W4t(64x128) -> tpw global (no activation)
    for (int nt = 0; nt < 8; ++nt) {
        f32x4 acc = {0.f, 0.f, 0.f, 0.f};
        #pragma unroll
        for (int ks = 0; ks < 2; ++ks) {
            s16x8 a = *(const s16x8*)(hA + arow + ks * 32);
            s16x8 b = *(const s16x8*)(sW + 9216 + nt * 16 * 72 + brow + ks * 32);
            acc = __builtin_amdgcn_mfma_f32_16x16x32_bf16(a, b, acc, 0, 0, 0);
        }
        #pragma unroll
        for (int r = 0; r < 4; ++r) {
            size_t row = e0 + r0 + (lane >> 4) * 4 + r;
            int col = nt * 16 + (lane & 15);
            tpw[row * 128 + col] = f2bf(acc[r]);
        }
    }
}

// K6a: CSR aggregation, one wave per node, m=0..3 only. agg bf16 (N,4,64).
__global__ __launch_bounds__(256) void agg_kernel(const float* __restrict__ angular,
                                                  const int* __restrict__ sender,
                                                  const int* __restrict__ offsets,
                                                  const int* __restrict__ edge_ids,
                                                  const ushort* __restrict__ x_ws,
                                                  const ushort* __restrict__ tpw,
                                                  ushort* __restrict__ agg) {
    int tid = threadIdx.x;
    int node = blockIdx.x * 4 + (tid >> 6);
    int lane = tid & 63;
    int m = lane >> 4, c0 = (lane & 15) * 4;
    int l = (m == 0) ? 0 : 1;
    float a0 = 0, a1 = 0, a2 = 0, a3 = 0;
    int beg = offsets[node], end = offsets[node + 1];
    int i = beg, eid = 0, s = 0;
    if (i < end) { eid = edge_ids[i]; s = sender[eid]; }
    while (i < end) {
        int ni = i + 1, neid = 0, ns = 0;
        if (ni < end) { neid = edge_ids[ni]; ns = sender[neid]; }
        float ang = angular[(size_t)eid * 16 + m];
        ushort4 xv = *(const ushort4*)(x_ws + (size_t)s * 64 + c0);
        ushort4 wv = *(const ushort4*)(tpw + (size_t)eid * 128 + l * 64 + c0);
        a0 += ang * bf2f(xv.x) * bf2f(wv.x);
        a1 += ang * bf2f(xv.y) * bf2f(wv.y);
        a2 += ang * bf2f(xv.z) * bf2f(wv.z);
        a3 += ang * bf2f(xv.w) * bf2f(wv.w);
        i = ni; eid = neid; s = ns;
    }
    ushort4 o;
    o.x = f2bf(a0 * 0.1f);
    o.y = f2bf(a1 * 0.1f);
    o.z = f2bf(a2 * 0.1f);
    o.w = f2bf(a3 * 0.1f);
    *(ushort4*)(agg + ((size_t)node * 4 + m) * 64 + c0) = o;
}

// K6b: per-32-node tile: feats = agg@W_lin (MFMA), scale by wn, out = f@W_p (+sc0).
__global__ __launch_bounds__(256) void node_out2_kernel(
    const float* __restrict__ nf, const float* __restrict__ one_hot,
    const float* __restrict__ W_lin, const float* __restrict__ W_skip,
    const float* __restrict__ W_c0, const float* __restrict__ W_c1,
    const float* __restrict__ W_p0, const float* __restrict__ W_p1,
    const ushort* __restrict__ agg, float* __restrict__ out) {
    __shared__ __align__(16) ushort sWl[2 * 64 * 72];
    __shared__ __align__(16) ushort sP[2 * 64 * 72];
    __shared__ __align__(16) ushort sF[4][32 * 72];
    __shared__ float sSc[32][64];
    __shared__ float sWc[2][640];
    __shared__ int sElem[32];
    int tid = threadIdx.x;
    int n0 = blockIdx.x * 32;

    for (int i = tid; i < 8192; i += 256) {
        int l = i >> 12, rem = i & 4095, k = rem >> 6, col = rem & 63;
        sWl[(l * 64 + col) * 72 + k] = f2bf(W_lin[l * 4096 + k * 64 + col]);
        const float* Wp = (l == 0) ? W_p0 : W_p1;
        sP[(l * 64 + col) * 72 + k] = f2bf(Wp[k * 64 + col]);
    }
    for (int i = tid; i < 1280; i += 256)
        sWc[i >= 640][i % 640] = (i >= 640 ? W_c1 : W_c0)[i % 640];
    if (tid < 32) {
        int nn = n0 + tid, e = 0;
        for (int a = 0; a < 10; ++a)
            if (one_hot[(size_t)nn * 10 + a] > 0.5f) { e = a; break; }
        sElem[tid] = e;
    }
    __syncthreads();

    // sc0 skip connection: 8 threads per node, 8 k's per thread
    {
        int nl = tid >> 3, k0 = (tid & 7) * 8;
        int nn = n0 + nl, elem = sElem[nl];
        float acc[8] = {0, 0, 0, 0, 0, 0, 0, 0};
        for (int c = 0; c < 64; ++c) {
            float v = nf[(size_t)nn * 64 + c];
            const float* wr = W_skip + ((size_t)c * 10 + elem) * 64 + k0;
            #pragma unroll
            for (int j = 0; j < 8; ++j) acc[j] += v * wr[j];
        }
        #pragma unroll
        for (int j = 0; j < 8; ++j) sSc[nl][k0 + j] = acc[j];
    }

    int lane = tid & 63, m = tid >> 6;
    int lsel = (m == 0) ? 0 : 1;

    // GEMM1: feats[m] = agg[:,m,:] @ W_lin[lsel]   (M=32, K=64, N=64)
    f32x4 acc[2][4] = {};
    s16x8 afr[2][2];
    #pragma unroll
    for (int mt = 0; mt < 2; ++mt)
        #pragma unroll
        for (int ks = 0; ks < 2; ++ks)
            afr[mt][ks] = *(const s16x8*)(agg +
                (((size_t)(n0 + mt * 16 + (lane & 15))) * 4 + m) * 64 +
                ks * 32 + (lane >> 4) * 8);
    #pragma unroll
    for (int nt = 0; nt < 4; ++nt)
        #pragma unroll
        for (int ks = 0; ks < 2; ++ks) {
            s16x8 b = *(const s16x8*)(sWl + (lsel * 64 + nt * 16 + (lane & 15)) * 72 +
                                      ks * 32 + (lane >> 4) * 8);
            #pragma unroll
            for (int mt = 0; mt < 2; ++mt)
                acc[mt][nt] = __builtin_amdgcn_mfma_f32_16x16x32_bf16(afr[mt][ks], b,
                                                                      acc[mt][nt], 0, 0, 0);
        }

    // scale by wn and write bf16 to sF
    #pragma unroll
    for (int mt = 0; mt < 2; ++mt)
        #pragma unroll
        for (int nt = 0; nt < 4; ++nt)
            #pragma unroll
            for (int r = 0; r < 4; ++r) {
                int nl = mt * 16 + (lane >> 4) * 4 + r;
                int k = nt * 16 + (lane & 15);
                float scale = sWc[lsel][sElem[nl] * 64 + k];
                sF[m][nl * 72 + k] = f2bf(acc[mt][nt][r] * scale);
            }
    __syncthreads();

    // GEMM2: out_m = f[m] @ W_p{0|1}
    f32x4 acc2[2][4] = {};
    s16x8 af2[2][2];
    #pragma unroll
    for (int mt = 0; mt < 2; ++mt)
        #pragma unroll
        for (int ks = 0; ks < 2; ++ks)
            af2[mt][ks] = *(const s16x8*)(&sF[m][(mt * 16 + (lane & 15)) * 72 +
                                                 ks * 32 + (lane >> 4) * 8]);
    #pragma unroll
    for (int nt = 0; nt < 4; ++nt)
        #pragma unroll
        for (int ks = 0; ks < 2; ++ks) {
            s16x8 b = *(const s16x8*)(sP + (lsel * 64 + nt * 16 + (lane & 15)) * 72 +
                                      ks * 32 + (lane >> 4) * 8);
            #pragma unroll
            for (int mt = 0; mt < 2; ++mt)
                acc2[mt][nt] = __builtin_amdgcn_mfma_f32_16x16x32_bf16(af2[mt][ks], b,
                                                                       acc2[mt][nt], 0, 0, 0);
        }

    // epilogue
    #pragma unroll
    for (int mt = 0; mt < 2; ++mt)
        #pragma unroll
        for (int nt = 0; nt < 4; ++nt)
            #pragma unroll
            for (int r = 0; r < 4; ++r) {
                int nl = mt * 16 + (lane >> 4) * 4 + r;
                int k = nt * 16 + (lane & 15);
                size_t nn = (size_t)n0 + nl;
                if (m == 0)
                    out[nn * 256 + k] = acc2[mt][nt][r] + sSc[nl][k];
                else
                    out[nn * 256 + 64 + k * 3 + (m - 1)] = acc2[mt][nt][r];
            }
}

extern "C" void kernel_launch(void* const* d_in, const int* in_sizes, int n_in,
                              void* d_out, int out_size, void* d_ws, size_t ws_size,
                              hipStream_t stream) {
    const float* node_features = (const float*)d_in[0];
    const float* one_hot = (const float*)d_in[1];
    const float* angular = (const float*)d_in[2];
    const float* radial = (const float*)d_in[3];
    const float* W_up = (const float*)d_in[4];
    const float* W_mlp1 = (const float*)d_in[5];
    const float* W_mlp2 = (const float*)d_in[6];
    const float* W_mlp3 = (const float*)d_in[7];
    const float* W_mlp4 = (const float*)d_in[8];
    const float* W_lin = (const float*)d_in[9];
    const float* W_skip = (const float*)d_in[10];
    const float* W_c0 = (const float*)d_in[11];
    const float* W_c1 = (const float*)d_in[12];
    const float* W_p0 = (const float*)d_in[13];
    const float* W_p1 = (const float*)d_in[14];
    const int* edge_index = (const int*)d_in[15];
    float* out = (float*)d_out;

    int N = in_sizes[0] / 64;
    int E = in_sizes[2] / 16;
    const int* sender = edge_index;
    const int* receiver = edge_index + E;

    char* p = (char*)d_ws;
    ushort* x_ws = (ushort*)p;  p += (size_t)N * 64 * 2;
    ushort* tpw = (ushort*)p;   p += (size_t)E * 128 * 2;
    ushort* agg = (ushort*)p;   p += (size_t)N * 4 * 64 * 2;
    ushort* wprep = (ushort*)p; p += 18432 * 2;
    int* counts = (int*)p;      p += (size_t)N * 4;
    int* offsets = (int*)p;     p += (size_t)(N + 1) * 4;
    int* cursor = (int*)p;      p += (size_t)N * 4;
    int* edge_ids = (int*)p;    p += (size_t)E * 4;

    hipMemsetAsync(counts, 0, (size_t)N * 4, stream);
    prep_kernel<<<72, 256, 0, stream>>>(W_mlp2, W_mlp3, W_mlp4, wprep);
    node_up_kernel<<<N / 4, 256, 0, stream>>>(node_features, W_up, x_ws);
    hist_kernel<<<(E + 255) / 256, 256, 0, stream>>>(receiver, counts, E);
    scan_kernel<<<1, 1024, 0, stream>>>(counts, offsets, cursor, N);
    scatter_kernel<<<(E + 255) / 256, 256, 0, stream>>>(receiver, cursor, edge_ids, E);
    edge_mlp_kernel<<<E / 64, 256, 0, stream>>>(radial, W_mlp1, wprep, tpw, E);
    agg_kernel<<<N / 4, 256, 0, stream>>>(angular, sender, offsets, edge_ids,
                                          x_ws, tpw, agg);
    node_out2_kernel<<<N / 32, 256, 0, stream>>>(node_features, one_hot, W_lin, W_skip,
                                                 W_c0, W_c1, W_p0, W_p1, agg, out);
}

// Round 3
// 196.150 us; speedup vs baseline: 2.7434x; 1.0597x over previous
//
#include <hip/hip_runtime.h>

typedef __attribute__((ext_vector_type(8))) short s16x8;
typedef __attribute__((ext_vector_type(4))) float f32x4;

__device__ inline float bf2f(ushort u) {
    union { unsigned int i; float f; } v; v.i = ((unsigned)u) << 16; return v.f;
}
__device__ inline ushort f2bf(float f) {
    union { float f; unsigned int i; } v; v.f = f;
    unsigned r = v.i + 0x7FFFu + ((v.i >> 16) & 1u);
    return (ushort)(r >> 16);
}
__device__ inline unsigned pack2(float a, float b) {
    return (unsigned)f2bf(a) | ((unsigned)f2bf(b) << 16);
}
__device__ inline float silu_f(float x) { return x / (1.f + __expf(-x)); }

// K1: x = node_features @ W_up, stored bf16. 4 nodes/block.
__global__ __launch_bounds__(256) void node_up_kernel(const float* __restrict__ nf,
                                                      const float* __restrict__ W_up,
                                                      ushort* __restrict__ x_ws) {
    __shared__ float sW[64 * 64];
    __shared__ float sNf[4][64];
    int tid = threadIdx.x;
    size_t n0 = (size_t)blockIdx.x * 4;
    for (int i = tid; i < 4096; i += 256) sW[i] = W_up[i];
    {
        int r = tid >> 6, c = tid & 63;
        sNf[r][c] = nf[(n0 + r) * 64 + c];
    }
    __syncthreads();
    int r = tid >> 6, k = tid & 63;
    float acc = 0.f;
    #pragma unroll 8
    for (int c = 0; c < 64; ++c) acc += sNf[r][c] * sW[c * 64 + k];
    x_ws[(n0 + r) * 64 + k] = f2bf(acc);
}

// K2: histogram of receivers
__global__ __launch_bounds__(256) void hist_kernel(const int* __restrict__ recv,
                                                   int* __restrict__ counts, int E) {
    int e = blockIdx.x * 256 + threadIdx.x;
    if (e < E) atomicAdd(&counts[recv[e]], 1);
}

// K3: single-pass chunked exclusive scan counts -> offsets (and cursor copy)
__global__ __launch_bounds__(1024) void scan_kernel(const int* __restrict__ counts,
                                                    int* __restrict__ offsets,
                                                    int* __restrict__ cursor, int n) {
    __shared__ int wsums[16];
    int tid = threadIdx.x, lane = tid & 63, wid = tid >> 6;
    int CH = (n + 1023) >> 10;
    int base = tid * CH;
    int tot = 0;
    for (int j = 0; j < CH; ++j) {
        int i = base + j;
        if (i < n) tot += counts[i];
    }
    int v = tot;
    for (int off = 1; off < 64; off <<= 1) {
        int t = __shfl_up(v, off, 64);
        if (lane >= off) v += t;
    }
    if (lane == 63) wsums[wid] = v;
    __syncthreads();
    if (tid == 0) {
        int acc = 0;
        for (int w = 0; w < 16; ++w) { int t = wsums[w]; wsums[w] = acc; acc += t; }
    }
    __syncthreads();
    int excl = wsums[wid] + v - tot;
    for (int j = 0; j < CH; ++j) {
        int i = base + j;
        if (i < n) { offsets[i] = excl; cursor[i] = excl; excl += counts[i]; }
    }
    if (tid == 1023) offsets[n] = excl;
}

// K4: scatter edge ids into CSR order + pre-gather sender and angular(float4, m=0..3)
__global__ __launch_bounds__(256) void scatter_kernel(const int* __restrict__ recv,
                                                      const int* __restrict__ sender,
                                                      const float* __restrict__ angular,
                                                      int* __restrict__ cursor,
                                                      int* __restrict__ edge_ids,
                                                      int* __restrict__ csr_sender,
                                                      float4* __restrict__ csr_ang, int E) {
    int e = blockIdx.x * 256 + threadIdx.x;
    if (e < E) {
        int pos = atomicAdd(&cursor[recv[e]], 1);
        edge_ids[pos] = e;
        csr_sender[pos] = sender[e];
        csr_ang[pos] = *(const float4*)(angular + (size_t)e * 16);
    }
}

// K_prep: bake bf16 weight images.
// wimg ushort layout:
//   [0,4096)      W1t  (64m x 64k, k<8 real else 0), A-side swizzle
//   [4096,8192)   W2t  (64 x 64)
//   [8192,12288)  W3t  (64 x 64)
//   [12288,20480) W4t  (128m x 64k)
//   [20480,29696) wl_img: (l*64+col)*72 + c  = W_lin[l][c][col]
//   [29696,38912) wp_img: (l*64+col)*72 + c  = W_p{l}[c][col]
__global__ __launch_bounds__(256) void prep_kernel(const float* __restrict__ W1,
                                                   const float* __restrict__ W2,
                                                   const float* __restrict__ W3,
                                                   const float* __restrict__ W4,
                                                   const float* __restrict__ W_lin,
                                                   const float* __restrict__ Wp0,
                                                   const float* __restrict__ Wp1,
                                                   ushort* __restrict__ wimg) {
    int idx = blockIdx.x * 256 + threadIdx.x;
    if (idx < 4096) {
        int m = idx >> 6, k = idx & 63;
        int dst = m * 64 + ((((k >> 3) ^ (m & 7))) << 3) + (k & 7);
        wimg[dst] = (k < 8) ? f2bf(W1[k * 64 + m]) : (ushort)0;
    } else if (idx < 8192) {
        int i = idx - 4096;
        int m = i >> 6, k = i & 63;
        int dst = 4096 + m * 64 + ((((k >> 3) ^ (m & 7))) << 3) + (k & 7);
        wimg[dst] = f2bf(W2[k * 64 + m]);
    } else if (idx < 12288) {
        int i = idx - 8192;
        int m = i >> 6, k = i & 63;
        int dst = 8192 + m * 64 + ((((k >> 3) ^ (m & 7))) << 3) + (k & 7);
        wimg[dst] = f2bf(W3[k * 64 + m]);
    } else if (idx < 20480) {
        int i = idx - 12288;
        int m = i >> 6, k = i & 63;  // m in 0..127
        int dst = 12288 + m * 64 + ((((k >> 3) ^ (m & 7))) << 3) + (k & 7);
        wimg[dst] = f2bf(W4[k * 256 + m]);
    } else if (idx < 29696) {
        int i = idx - 20480;
        int row = i / 72, k = i % 72;
        int l = row >> 6, col = row & 63;
        wimg[idx] = (k < 64) ? f2bf(W_lin[l * 4096 + k * 64 + col]) : (ushort)0;
    } else if (idx < 38912) {
        int i = idx - 29696;
        int row = i / 72, k = i % 72;
        int l = row >> 6, col = row & 63;
        const float* Wp = l ? Wp1 : Wp0;
        wimg[idx] = (k < 64) ? f2bf(Wp[k * 64 + col]) : (ushort)0;
    }
}

// K5: edge MLP, operand-swapped (D = W^T h^T). Each wave owns 16 edges end-to-end.
// CSR order: processes edge_ids[i], writes tpw[i] (128 cols: l=0,1).
__global__ __launch_bounds__(256) void edge_mlp_kernel(const float* __restrict__ radial,
                                                       const ushort* __restrict__ wimg,
                                                       const int* __restrict__ edge_ids,
                                                       ushort* __restrict__ tpw, int E) {
    __shared__ __align__(16) ushort sW4[8192];
    __shared__ __align__(16) ushort sB[4][2048];  // per-wave bounce, 4KB each
    int tid = threadIdx.x, lane = tid & 63, wave = tid >> 6;
    int n = lane & 15, hi = lane >> 4;

    for (int i = tid; i < 1024; i += 256)
        ((s16x8*)sW4)[i] = ((const s16x8*)(wimg + 12288))[i];

    // preload A-side weight fragments (VGPR-resident, block-invariant)
    s16x8 w1f[4], w2f[4][2], w3f[4][2];
    #pragma unroll
    for (int mt = 0; mt < 4; ++mt) {
        int row = mt * 16 + n, r7 = row & 7;
        w1f[mt] = *(const s16x8*)(wimg + row * 64 + ((hi ^ r7) << 3));
        #pragma unroll
        for (int ks = 0; ks < 2; ++ks) {
            w2f[mt][ks] = *(const s16x8*)(wimg + 4096 + row * 64 + (((ks * 4 + hi) ^ r7) << 3));
            w3f[mt][ks] = *(const s16x8*)(wimg + 8192 + row * 64 + (((ks * 4 + hi) ^ r7) << 3));
        }
    }
    __syncthreads();

    char* myB = (char*)sB[wave];
    int n7 = n & 7;

    for (int pass = 0; pass < 4; ++pass) {
        int base = blockIdx.x * 256 + pass * 64 + wave * 16;
        if (base >= E) break;
        int ipos = base + n;
        int eid = edge_ids[min(ipos, E - 1)];

        // radial B-fragment (k = hi*8+j; only k<8 real)
        s16x8 bR;
        #pragma unroll
        for (int j = 0; j < 8; ++j) bR[j] = 0;
        if (hi == 0) {
            float4 r0 = *(const float4*)(radial + (size_t)eid * 8);
            float4 r1 = *(const float4*)(radial + (size_t)eid * 8 + 4);
            bR[0] = (short)f2bf(r0.x); bR[1] = (short)f2bf(r0.y);
            bR[2] = (short)f2bf(r0.z); bR[3] = (short)f2bf(r0.w);
            bR[4] = (short)f2bf(r1.x); bR[5] = (short)f2bf(r1.y);
            bR[6] = (short)f2bf(r1.z); bR[7] = (short)f2bf(r1.w);
        }

        f32x4 zero = {0.f, 0.f, 0.f, 0.f};
        f32x4 d[4];
        // L1 (K=32, zero-padded)
        #pragma unroll
        for (int mt = 0; mt < 4; ++mt)
            d[mt] = __builtin_amdgcn_mfma_f32_16x16x32_bf16(w1f[mt], bR, zero, 0, 0, 0);

        // silu -> bounce (h rows: 128B, 8 slots, slot ^= n&7)
        #pragma unroll
        for (int mt = 0; mt < 4; ++mt) {
            unsigned p0 = pack2(silu_f(d[mt][0]), silu_f(d[mt][1]));
            unsigned p1 = pack2(silu_f(d[mt][2]), silu_f(d[mt][3]));
            int slot = mt * 2 + (hi >> 1);
            uint2 val = {p0, p1};
            *(uint2*)(myB + n * 128 + ((slot ^ n7) << 4) + (hi & 1) * 8) = val;
        }
        s16x8 b0 = *(const s16x8*)(myB + n * 128 + ((hi ^ n7) << 4));
        s16x8 b1 = *(const s16x8*)(myB + n * 128 + (((4 + hi) ^ n7) << 4));

        // L2
        #pragma unroll
        for (int mt = 0; mt < 4; ++mt) {
            d[mt] = __builtin_amdgcn_mfma_f32_16x16x32_bf16(w2f[mt][0], b0, zero, 0, 0, 0);
            d[mt] = __builtin_amdgcn_mfma_f32_16x16x32_bf16(w2f[mt][1], b1, d[mt], 0, 0, 0);
        }
        #pragma unroll
        for (int mt = 0; mt < 4; ++mt) {
            unsigned p0 = pack2(silu_f(d[mt][0]), silu_f(d[mt][1]));
            unsigned p1 = pack2(silu_f(d[mt][2]), silu_f(d[mt][3]));
            int slot = mt * 2 + (hi >> 1);
            uint2 val = {p0, p1};
            *(uint2*)(myB + n * 128 + ((slot ^ n7) << 4) + (hi & 1) * 8) = val;
        }
        b0 = *(const s16x8*)(myB + n * 128 + ((hi ^ n7) << 4));
        b1 = *(const s16x8*)(myB + n * 128 + (((4 + hi) ^ n7) << 4));

        // L3
        #pragma unroll
        for (int mt = 0; mt < 4; ++mt) {
            d[mt] = __builtin_amdgcn_mfma_f32_16x16x32_bf16(w3f[mt][0], b0, zero, 0, 0, 0);
            d[mt] = __builtin_amdgcn_mfma_f32_16x16x32_bf16(w3f[mt][1], b1, d[mt], 0, 0, 0);
        }
        #pragma unroll
        for (int mt = 0; mt < 4; ++mt) {
            unsigned p0 = pack2(silu_f(d[mt][0]), silu_f(d[mt][1]));
            unsigned p1 = pack2(silu_f(d[mt][2]), silu_f(d[mt][3]));
            int slot = mt * 2 + (hi >> 1);
            uint2 val = {p0, p1};
            *(uint2*)(myB + n * 128 + ((slot ^ n7) << 4) + (hi & 1) * 8) = val;
        }
        b0 = *(const s16x8*)(myB + n * 128 + ((hi ^ n7) << 4));
        b1 = *(const s16x8*)(myB + n * 128 + (((4 + hi) ^ n7) << 4));

        // L4: 128 outputs, A from LDS sW4
        f32x4 o[8];
        #pragma unroll
        for (int mt = 0; mt < 8; ++mt) {
            int row = mt * 16 + n, r7 = row & 7;
            s16x8 a0 = *(const s16x8*)(sW4 + row * 64 + ((hi ^ r7) << 3));
            s16x8 a1 = *(const s16x8*)(sW4 + row * 64 + (((4 + hi) ^ r7) << 3));
            o[mt] = __builtin_amdgcn_mfma_f32_16x16x32_bf16(a0, b0, zero, 0, 0, 0);
            o[mt] = __builtin_amdgcn_mfma_f32_16x16x32_bf16(a1, b1, o[mt], 0, 0, 0);
        }
        // pack to bounce (256B rows, 16 slots, slot ^= n full 4 bits)
        #pragma unroll
        for (int mt = 0; mt < 8; ++mt) {
            unsigned p0 = pack2(o[mt][0], o[mt][1]);
            unsigned p1 = pack2(o[mt][2], o[mt][3]);
            int slot = mt * 2 + (hi >> 1);
            uint2 val = {p0, p1};
            *(uint2*)(myB + n * 256 + ((slot ^ n) << 4) + (hi & 1) * 8) = val;
        }
        // coalesced store: 4 rows per sweep
        #pragma unroll
        for (int p = 0; p < 4; ++p) {
            int row = p * 4 + hi;
            s16x8 v = *(const s16x8*)(myB + row * 256 + (((lane & 15) ^ row) << 4));
            int grow = base + row;
            if (grow < E)
                *(s16x8*)(tpw + (size_t)grow * 128 + (lane & 15) * 8) = v;
        }
    }
}

// K6a: CSR aggregation. Wave per node, lane = channel, 4 m-accumulators.
__global__ __launch_bounds__(256) void agg_kernel(const float4* __restrict__ csr_ang,
                                                  const int* __restrict__ csr_sender,
                                                  const ushort* __restrict__ tpw,
                                                  const int* __restrict__ offsets,
                                                  const ushort* __restrict__ x_ws,
                                                  ushort* __restrict__ agg, int N) {
    int wave = threadIdx.x >> 6, lane = threadIdx.x & 63;
    int node = blockIdx.x * 4 + wave;
    if (node >= N) return;
    int beg = offsets[node], end = offsets[node + 1];
    float a0 = 0, a1 = 0, a2 = 0, a3 = 0;
    int s = (beg < end) ? csr_sender[beg] : 0;
    float xcur = (beg < end) ? bf2f(x_ws[(size_t)s * 64 + lane]) : 0.f;
    for (int i = beg; i < end; ++i) {
        int sn = (i + 1 < end) ? csr_sender[i + 1] : 0;
        float xn = (i + 1 < end) ? bf2f(x_ws[(size_t)sn * 64 + lane]) : 0.f;
        float4 ang = csr_ang[i];
        float tp0 = bf2f(tpw[(size_t)i * 128 + lane]);
        float tp1 = bf2f(tpw[(size_t)i * 128 + 64 + lane]);
        float y0 = xcur * tp0, y1 = xcur * tp1;
        a0 += ang.x * y0;
        a1 += ang.y * y1;
        a2 += ang.z * y1;
        a3 += ang.w * y1;
        xcur = xn;
    }
    size_t b = (size_t)node * 256 + lane;
    agg[b] = f2bf(a0 * 0.1f);
    agg[b + 64] = f2bf(a1 * 0.1f);
    agg[b + 128] = f2bf(a2 * 0.1f);
    agg[b + 192] = f2bf(a3 * 0.1f);
}

// K6b: per-32-node tile: feats = agg@W_lin (MFMA), scale by wn, out = f@W_p (+sc0).
__global__ __launch_bounds__(256) void node_out2_kernel(
    const float* __restrict__ nf, const float* __restrict__ one_hot,
    const ushort* __restrict__ wimg, const float* __restrict__ W_skip,
    const float* __restrict__ W_c0, const float* __restrict__ W_c1,
    const ushort* __restrict__ agg, float* __restrict__ out) {
    __shared__ __align__(16) ushort sWl[2 * 64 * 72];
    __shared__ __align__(16) ushort sF[4][32 * 72];
    __shared__ float sSc[32][64];
    __shared__ float sWc[2][640];
    __shared__ int sElem[32];
    int tid = threadIdx.x;
    int n0 = blockIdx.x * 32;
    int lane = tid & 63, m = tid >> 6;
    int lsel = (m == 0) ? 0 : 1;

    // direct-from-global W_p B-fragments (L2-resident image)
    s16x8 pf[4][2];
    #pragma unroll
    for (int nt = 0; nt < 4; ++nt)
        #pragma unroll
        for (int ks = 0; ks < 2; ++ks)
            pf[nt][ks] = *(const s16x8*)(wimg + 29696 +
                (lsel * 64 + nt * 16 + (lane & 15)) * 72 + ks * 32 + (lane >> 4) * 8);

    for (int i = tid; i < 1152; i += 256)
        ((s16x8*)sWl)[i] = ((const s16x8*)(wimg + 20480))[i];
    for (int i = tid; i < 1280; i += 256)
        sWc[i >= 640][i % 640] = (i >= 640 ? W_c1 : W_c0)[i % 640];
    if (tid < 32) {
        int nn = n0 + tid, e = 0;
        for (int a = 0; a < 10; ++a)
            if (one_hot[(size_t)nn * 10 + a] > 0.5f) { e = a; break; }
        sElem[tid] = e;
    }
    __syncthreads();

    // sc0 skip connection: 8 threads per node, 8 k's per thread
    {
        int nl = tid >> 3, k0 = (tid & 7) * 8;
        int nn = n0 + nl, elem = sElem[nl];
        float acc[8] = {0, 0, 0, 0, 0, 0, 0, 0};
        for (int c = 0; c < 64; ++c) {
            float v = nf[(size_t)nn * 64 + c];
            const float* wr = W_skip + ((size_t)c * 10 + elem) * 64 + k0;
            #pragma unroll
            for (int j = 0; j < 8; ++j) acc[j] += v * wr[j];
        }
        #pragma unroll
        for (int j = 0; j < 8; ++j) sSc[nl][k0 + j] = acc[j];
    }

    // GEMM1: feats[m] = agg[:,m,:] @ W_lin[lsel]   (M=32, K=64, N=64)
    f32x4 acc[2][4] = {};
    s16x8 afr[2][2];
    #pragma unroll
    for (int mt = 0; mt < 2; ++mt)
        #pragma unroll
        for (int ks = 0; ks < 2; ++ks)
            afr[mt][ks] = *(const s16x8*)(agg +
                (((size_t)(n0 + mt * 16 + (lane & 15))) * 4 + m) * 64 +
                ks * 32 + (lane >> 4) * 8);
    #pragma unroll
    for (int nt = 0; nt < 4; ++nt)
        #pragma unroll
        for (int ks = 0; ks < 2; ++ks) {
            s16x8 b = *(const s16x8*)(sWl + (lsel * 64 + nt * 16 + (lane & 15)) * 72 +
                                      ks * 32 + (lane >> 4) * 8);
            #pragma unroll
            for (int mt = 0; mt < 2; ++mt)
                acc[mt][nt] = __builtin_amdgcn_mfma_f32_16x16x32_bf16(afr[mt][ks], b,
                                                                      acc[mt][nt], 0, 0, 0);
        }

    // scale by wn and write bf16 to sF
    #pragma unroll
    for (int mt = 0; mt < 2; ++mt)
        #pragma unroll
        for (int nt = 0; nt < 4; ++nt)
            #pragma unroll
            for (int r = 0; r < 4; ++r) {
                int nl = mt * 16 + (lane >> 4) * 4 + r;
                int k = nt * 16 + (lane & 15);
                float scale = sWc[lsel][sElem[nl] * 64 + k];
                sF[m][nl * 72 + k] = f2bf(acc[mt][nt][r] * scale);
            }
    __syncthreads();

    // GEMM2: out_m = f[m] @ W_p{0|1}
    f32x4 acc2[2][4] = {};
    s16x8 af2[2][2];
    #pragma unroll
    for (int mt = 0; mt < 2; ++mt)
        #pragma unroll
        for (int ks = 0; ks < 2; ++ks)
            af2[mt][ks] = *(const s16x8*)(&sF[m][(mt * 16 + (lane & 15)) * 72 +
                                                 ks * 32 + (lane >> 4) * 8]);
    #pragma unroll
    for (int nt = 0; nt < 4; ++nt)
        #pragma unroll
        for (int ks = 0; ks < 2; ++ks) {
            #pragma unroll
            for (int mt = 0; mt < 2; ++mt)
                acc2[mt][nt] = __builtin_amdgcn_mfma_f32_16x16x32_bf16(af2[mt][ks],
                                                                       pf[nt][ks],
                                                                       acc2[mt][nt], 0, 0, 0);
        }

    // epilogue
    #pragma unroll
    for (int mt = 0; mt < 2; ++mt)
        #pragma unroll
        for (int nt = 0; nt < 4; ++nt)
            #pragma unroll
            for (int r = 0; r < 4; ++r) {
                int nl = mt * 16 + (lane >> 4) * 4 + r;
                int k = nt * 16 + (lane & 15);
                size_t nn = (size_t)n0 + nl;
                if (m == 0)
                    out[nn * 256 + k] = acc2[mt][nt][r] + sSc[nl][k];
                else
                    out[nn * 256 + 64 + k * 3 + (m - 1)] = acc2[mt][nt][r];
            }
}

extern "C" void kernel_launch(void* const* d_in, const int* in_sizes, int n_in,
                              void* d_out, int out_size, void* d_ws, size_t ws_size,
                              hipStream_t stream) {
    const float* node_features = (const float*)d_in[0];
    const float* one_hot = (const float*)d_in[1];
    const float* angular = (const float*)d_in[2];
    const float* radial = (const float*)d_in[3];
    const float* W_up = (const float*)d_in[4];
    const float* W_mlp1 = (const float*)d_in[5];
    const float* W_mlp2 = (const float*)d_in[6];
    const float* W_mlp3 = (const float*)d_in[7];
    const float* W_mlp4 = (const float*)d_in[8];
    const float* W_lin = (const float*)d_in[9];
    const float* W_skip = (const float*)d_in[10];
    const float* W_c0 = (const float*)d_in[11];
    const float* W_c1 = (const float*)d_in[12];
    const float* W_p0 = (const float*)d_in[13];
    const float* W_p1 = (const float*)d_in[14];
    const int* edge_index = (const int*)d_in[15];
    float* out = (float*)d_out;

    int N = in_sizes[0] / 64;
    int E = in_sizes[2] / 16;
    const int* sender = edge_index;
    const int* receiver = edge_index + E;

    char* p = (char*)d_ws;
    ushort* x_ws = (ushort*)p;    p += (size_t)N * 64 * 2;
    ushort* tpw = (ushort*)p;     p += (size_t)E * 128 * 2;
    ushort* agg = (ushort*)p;     p += (size_t)N * 256 * 2;
    ushort* wimg = (ushort*)p;    p += 38912 * 2;
    float4* csr_ang = (float4*)p; p += (size_t)E * 16;
    int* counts = (int*)p;        p += (size_t)N * 4;
    int* offsets = (int*)p;       p += (size_t)(N + 1) * 4;
    int* cursor = (int*)p;        p += (size_t)N * 4;
    int* edge_ids = (int*)p;      p += (size_t)E * 4;
    int* csr_sender = (int*)p;    p += (size_t)E * 4;

    hipMemsetAsync(counts, 0, (size_t)N * 4, stream);
    prep_kernel<<<152, 256, 0, stream>>>(W_mlp1, W_mlp2, W_mlp3, W_mlp4,
                                         W_lin, W_p0, W_p1, wimg);
    node_up_kernel<<<N / 4, 256, 0, stream>>>(node_features, W_up, x_ws);
    hist_kernel<<<(E + 255) / 256, 256, 0, stream>>>(receiver, counts, E);
    scan_kernel<<<1, 1024, 0, stream>>>(counts, offsets, cursor, N);
    scatter_kernel<<<(E + 255) / 256, 256, 0, stream>>>(receiver, sender, angular,
                                                        cursor, edge_ids, csr_sender,
                                                        csr_ang, E);
    edge_mlp_kernel<<<(E + 255) / 256, 256, 0, stream>>>(radial, wimg, edge_ids, tpw, E);
    agg_kernel<<<(N + 3) / 4, 256, 0, stream>>>(csr_ang, csr_sender, tpw, offsets,
                                                x_ws, agg, N);
    node_out2_kernel<<<N / 32, 256, 0, stream>>>(node_features, one_hot, wimg, W_skip,
                                                 W_c0, W_c1, agg, out);
}